// Round 2
// baseline (135.974 us; speedup 1.0000x reference)
//
#include <hip/hip_runtime.h>
#include <math.h>

// PhaseShift: out = unwrap(atan2(xi,xr) - atan2(xi[ch0],xr[ch0]), axis=F)
// Shapes: [N=16, CH=4, F=513, T=512] fp32.
// Block = (n, ch, t-tile of 64): 1024 threads = 16 waves; wave w owns
// F-segment [w*33, w*33+33) (reads clamped at F-1; clamped rows give dd=0
// -> correction 0). Pass 1 computes q[k] = phase_diff + local correction
// prefix into REGISTERS (static indexing, unconditional writes -> SROA).
// LDS scan of the 16 per-segment correction sums gives the cross-segment
// offset; pass 2 is q[k] + offset -> store. Channel 0 is exactly zero.

#define NN   16
#define CHN  4
#define FF   513
#define TT   512
#define NSEG 16
#define SEG  33   // ceil(513/16)

__device__ __forceinline__ float phase_corr(float dd) {
    // Faithful np.unwrap step in fp32:
    // ddmod = mod(dd+pi, 2pi) - pi  (python-mod: fmod + negative fixup)
    // if (ddmod == -pi && dd > 0) ddmod = pi
    // return |dd| < pi ? 0 : ddmod - dd
    const float PIF  = 3.14159265358979323846f;   // 0x40490FDB
    const float TPIF = 6.28318530717958647692f;   // 0x40C90FDB = 2*PIF exactly
    float m = fmodf(dd + PIF, TPIF);
    m = (m < 0.0f) ? m + TPIF : m;
    float ddmod = m - PIF;
    if (ddmod == -PIF && dd > 0.0f) ddmod = PIF;
    return (fabsf(dd) < PIF) ? 0.0f : (ddmod - dd);
}

__global__ __launch_bounds__(1024, 4) void phase_unwrap_kernel(
    const float* __restrict__ xr, const float* __restrict__ xi,
    float* __restrict__ out)
{
    const int tid   = threadIdx.x;
    const int wave  = tid >> 6;     // 0..15 = F-segment id
    const int lane  = tid & 63;
    const int bid   = blockIdx.x;
    const int ttile = bid & 7;      // 8 tiles of 64 t
    const int ch    = (bid >> 3) & 3;
    const int n     = bid >> 5;
    const int t     = ttile * 64 + lane;

    // 32-bit element offsets: max index 16*4*513*512 = 16.8M << 2^32
    const unsigned colC = (unsigned)((n * CHN + ch) * (FF * TT)) + (unsigned)t;
    const unsigned col0 = (unsigned)((n * CHN) * (FF * TT)) + (unsigned)t;

    const int f0 = wave * SEG;

    if (ch == 0) {
        // phase - phase[:, :1] == 0 exactly; unwrap(0) == 0.
        #pragma unroll
        for (int k = 0; k < SEG; ++k) {
            const int f = f0 + k;
            if (f < FF) out[colC + (unsigned)f * TT] = 0.0f;
        }
        return;  // block-uniform path: no barrier needed
    }

    __shared__ float segsum[NSEG][64];

    float q[SEG];

    // Boundary phase (f0-1) for the segment-crossing dd (waves 1..15).
    float pbound = 0.0f;
    if (wave > 0) {
        const unsigned off = (unsigned)(f0 - 1) * TT;
        pbound = atan2f(xi[colC + off], xr[colC + off])
               - atan2f(xi[col0 + off], xr[col0 + off]);
    }

    // Pass 1: q[k] = phase_diff + inclusive local correction prefix.
    float acc   = 0.0f;
    float pprev = pbound;
    #pragma unroll
    for (int k = 0; k < SEG; ++k) {
        int f = f0 + k;
        f = (f < FF) ? f : (FF - 1);             // clamp: dup row -> dd=0 -> corr=0
        const unsigned off = (unsigned)f * TT;
        const float pc = atan2f(xi[colC + off], xr[colC + off])
                       - atan2f(xi[col0 + off], xr[col0 + off]);
        const float c = phase_corr(pc - pprev);
        if (k > 0 || wave > 0)                   // k>0 folds at compile time
            acc += c;
        q[k] = pc + acc;
        pprev = pc;
    }

    // Cross-segment exclusive prefix of correction sums (16 values per t).
    segsum[wave][lane] = acc;
    __syncthreads();
    float run = 0.0f;
    for (int v = 0; v < wave; ++v)
        run += segsum[v][lane];
    // subtract own acc back out: q already contains the local prefix
    // (run is exclusive: sums waves v < wave only)

    // Pass 2: pure add + store.
    #pragma unroll
    for (int k = 0; k < SEG; ++k) {
        const int f = f0 + k;
        if (f < FF)
            out[colC + (unsigned)f * TT] = q[k] + run;
    }
}

extern "C" void kernel_launch(void* const* d_in, const int* in_sizes, int n_in,
                              void* d_out, int out_size, void* d_ws, size_t ws_size,
                              hipStream_t stream) {
    const float* xr = (const float*)d_in[0];
    const float* xi = (const float*)d_in[1];
    float* out = (float*)d_out;

    dim3 grid(NN * CHN * (TT / 64));   // 512 blocks
    dim3 block(1024);                  // 16 waves = 16 F-segments
    phase_unwrap_kernel<<<grid, block, 0, stream>>>(xr, xi, out);
}

// Round 3
// 71.132 us; speedup vs baseline: 1.9116x; 1.9116x over previous
//
#include <hip/hip_runtime.h>
#include <math.h>

// PhaseShift: out = unwrap(atan2(xi,xr) - atan2(xi[ch0],xr[ch0]), axis=F)
// Shapes: [N=16, CH=4, F=513, T=512] fp32.
//
// Block = (n, ch, t-tile of 64): 1024 threads = 16 waves; wave w owns
// F-segment [w*33, min(w*33+33, 513)). NO per-thread arrays (R1/R2 both
// spilled them to scratch: +180MB HBM traffic in R2). Pass 1 streams:
// pc = phase_diff, acc += correction, store out[f] = pc + acc. LDS scan
// of the 16 per-segment correction sums; pass 2 RMWs out[f] += offset
// (waves 1..15; the re-read is L2-resident). Channel 0 is exactly zero.

#define NN   16
#define CHN  4
#define FF   513
#define TT   512
#define NSEG 16
#define SEG  33   // ceil(513/16)

__device__ __forceinline__ float phase_corr(float dd) {
    // Faithful np.unwrap step in fp32:
    // ddmod = mod(dd+pi, 2pi) - pi  (python-mod: fmod + negative fixup)
    // if (ddmod == -pi && dd > 0) ddmod = pi
    // return |dd| < pi ? 0 : ddmod - dd
    const float PIF  = 3.14159265358979323846f;   // 0x40490FDB
    const float TPIF = 6.28318530717958647692f;   // 0x40C90FDB = 2*PIF exactly
    float m = fmodf(dd + PIF, TPIF);
    m = (m < 0.0f) ? m + TPIF : m;
    float ddmod = m - PIF;
    if (ddmod == -PIF && dd > 0.0f) ddmod = PIF;
    return (fabsf(dd) < PIF) ? 0.0f : (ddmod - dd);
}

__global__ __launch_bounds__(1024, 8) void phase_unwrap_kernel(
    const float* __restrict__ xr, const float* __restrict__ xi,
    float* __restrict__ out)
{
    const int tid   = threadIdx.x;
    const int wave  = tid >> 6;     // 0..15 = F-segment id
    const int lane  = tid & 63;
    const int bid   = blockIdx.x;
    const int ttile = bid & 7;      // 8 tiles of 64 t
    const int ch    = (bid >> 3) & 3;
    const int n     = bid >> 5;

    const unsigned plane  = (unsigned)((n * CHN + ch) * (FF * TT));
    const unsigned plane0 = (unsigned)((n * CHN) * (FF * TT));

    if (ch == 0) {
        // phase - phase[:, :1] == 0 exactly; unwrap(0) == 0. float4 fill.
        float4* out4 = (float4*)out;
        const unsigned base4 = (plane >> 2) + (unsigned)(ttile * 16);
        const float4 z = make_float4(0.f, 0.f, 0.f, 0.f);
        for (int idx = tid; idx < FF * 16; idx += 1024) {
            const int row = idx >> 4, g = idx & 15;
            out4[base4 + (unsigned)row * (TT / 4) + (unsigned)g] = z;
        }
        return;  // block-uniform path: no barrier needed
    }

    const int t = ttile * 64 + lane;
    const unsigned colC = plane  + (unsigned)t;
    const unsigned col0 = plane0 + (unsigned)t;

    const int f0  = wave * SEG;
    const int cnt = min(SEG, FF - f0);   // 33, last wave 18

    __shared__ float segsum[NSEG][64];

    // Boundary phase (f0-1) for the segment-crossing dd (waves 1..15).
    float pprev = 0.0f;
    if (wave > 0) {
        const unsigned off = (unsigned)(f0 - 1) * TT;
        pprev = atan2f(xi[colC + off], xr[colC + off])
              - atan2f(xi[col0 + off], xr[col0 + off]);
    }

    // Pass 1: stream pc, accumulate local correction prefix, store pc+acc.
    float acc = 0.0f;
    #pragma unroll 4
    for (int k = 0; k < cnt; ++k) {
        const unsigned off = (unsigned)(f0 + k) * TT;
        const float pc = atan2f(xi[colC + off], xr[colC + off])
                       - atan2f(xi[col0 + off], xr[col0 + off]);
        if (wave > 0 || k > 0)
            acc += phase_corr(pc - pprev);
        out[colC + off] = pc + acc;
        pprev = pc;
    }

    // Cross-segment exclusive prefix of correction sums (16 values per t).
    segsum[wave][lane] = acc;
    __syncthreads();

    if (wave > 0) {
        float run = 0.0f;
        for (int v = 0; v < wave; ++v)
            run += segsum[v][lane];
        // Pass 2: RMW our freshly-written (L2-resident) subtile.
        #pragma unroll 4
        for (int k = 0; k < cnt; ++k) {
            const unsigned off = (unsigned)(f0 + k) * TT;
            out[colC + off] += run;
        }
    }
}

extern "C" void kernel_launch(void* const* d_in, const int* in_sizes, int n_in,
                              void* d_out, int out_size, void* d_ws, size_t ws_size,
                              hipStream_t stream) {
    const float* xr = (const float*)d_in[0];
    const float* xi = (const float*)d_in[1];
    float* out = (float*)d_out;

    dim3 grid(NN * CHN * (TT / 64));   // 512 blocks = 2 blocks/CU
    dim3 block(1024);                  // 16 waves = 16 F-segments
    phase_unwrap_kernel<<<grid, block, 0, stream>>>(xr, xi, out);
}